// Round 2
// baseline (362.168 us; speedup 1.0000x reference)
//
#include <hip/hip_runtime.h>
#include <hip/hip_bf16.h>

namespace {

constexpr int Sseq = 2048;
constexpr int NH   = 16;
constexpr int HD   = 64;
constexpr int ROW  = NH * HD;      // 1024 floats between consecutive s
constexpr int BM   = 64;           // q rows per block (1 m-tile per wave)
constexpr int BN   = 64;           // kv rows per tile
constexpr int MT   = 1;            // 16-row m-tiles per wave
constexpr float QSCALE = 0.18033688011112042f; // (1/8) * log2(e)

typedef __bf16 bf16_t;
typedef __attribute__((ext_vector_type(8))) bf16_t bf16x8;
typedef __attribute__((ext_vector_type(4))) float f32x4;
typedef __attribute__((ext_vector_type(2))) unsigned int u32x2;

union Frag { bf16x8 v; unsigned int u[4]; };

__device__ inline unsigned int pkbf(float a, float b) {
  union { __hip_bfloat162 h; unsigned int u; } x;
  x.h = __float22bfloat162_rn(make_float2(a, b));
  return x.u;
}

// Layout notes (verified mappings from cdna_hip_programming.md §3):
//  mfma_f32_16x16x32_bf16: A[m=lane&15][k=quad*8+j], B[k=quad*8+j][n=lane&15],
//  C/D: col=lane&15, row=quad*4+reg.
// We compute S^T = K·Q^T so C col = q-row (lane&15); softmax state is a lane
// scalar. Then O^T = V^T·P^T with A=V^T (LDS, transposed at staging) and
// B=P^T read from LDS P[m][n] rows (8 contiguous n -> ds_read_b128).
// LDS rows are 128B with 16B-chunk XOR swizzle (chunk ^= row&7) so all frag
// reads/writes spread across all 8 bank groups.
//
// R2: grid was the occupancy cap (512 blocks = 2 blocks/CU = 22.8% occ).
// BM 128->64 (MT 2->1) doubles grid to 1024 -> 4 blocks/CU, 16 waves/CU.

__global__ __launch_bounds__(256)
void fa_fwd(const float* __restrict__ Q, const float* __restrict__ K,
            const float* __restrict__ V, float* __restrict__ O) {
  const int id   = blockIdx.x;
  const int bh   = id & 31;           // b*16 + h ; XCD = id % 8 = bh % 8
  const int qblk = id >> 5;
  const int tid  = threadIdx.x;
  const int wave = tid >> 6;
  const int lane = tid & 63;
  const int qd   = lane >> 4;         // quad
  const int lm   = lane & 15;

  const size_t base = (size_t)(bh >> 4) * Sseq * ROW + (size_t)(bh & 15) * HD;
  const float* qb = Q + base;
  const float* kb = K + base;
  const float* vb = V + base;
  float*       ob = O + base;

  __shared__ __align__(16) unsigned short VT[2][HD * 64];     // V^T bf16 (dbuf) 16KB
  __shared__ __align__(16) unsigned short PB[4][MT][16 * 64]; // per-wave P 8KB

  const int qrow0 = qblk * BM + wave * (MT * 16);

  // Q B-fragments, pre-scaled by (1/sqrt(D))*log2(e) so p = exp2(s)
  Frag qf[MT][2];
  for (int mt = 0; mt < MT; ++mt) {
    const float* qp = qb + (size_t)(qrow0 + mt * 16 + lm) * ROW;
    for (int ks = 0; ks < 2; ++ks) {
      f32x4 a = *(const f32x4*)(qp + ks * 32 + qd * 8);
      f32x4 c = *(const f32x4*)(qp + ks * 32 + qd * 8 + 4);
      qf[mt][ks].u[0] = pkbf(a[0] * QSCALE, a[1] * QSCALE);
      qf[mt][ks].u[1] = pkbf(a[2] * QSCALE, a[3] * QSCALE);
      qf[mt][ks].u[2] = pkbf(c[0] * QSCALE, c[1] * QSCALE);
      qf[mt][ks].u[3] = pkbf(c[2] * QSCALE, c[3] * QSCALE);
    }
  }

  f32x4 oacc[MT][4] = {};
  float lsum[MT] = {};

  const int n4 = (tid & 15) * 4;      // V staging: 4 n-rows x 4 d-cols / thread
  const int d4 = (tid >> 4) * 4;

  for (int t = 0; t < Sseq / BN; ++t) {
    const int kv0 = t * BN;

    { // stage V^T (bf16, swizzled) into VT[t&1]
      const float* vp = vb + (size_t)(kv0 + n4) * ROW + d4;
      f32x4 r0 = *(const f32x4*)(vp);
      f32x4 r1 = *(const f32x4*)(vp + ROW);
      f32x4 r2 = *(const f32x4*)(vp + 2 * ROW);
      f32x4 r3 = *(const f32x4*)(vp + 3 * ROW);
      unsigned short* vt = VT[t & 1];
      #pragma unroll
      for (int i = 0; i < 4; ++i) {
        int d = d4 + i;
        int chunk = (n4 >> 3) ^ (d & 7);
        u32x2 val; val.x = pkbf(r0[i], r1[i]); val.y = pkbf(r2[i], r3[i]);
        *(u32x2*)(vt + d * 64 + chunk * 8 + (n4 & 7)) = val;
      }
    }

    // K A-fragments straight from global (L1/L2 absorbs 4-wave reuse)
    Frag kf[4][2];
    {
      const float* kp = kb + (size_t)(kv0 + lm) * ROW;
      #pragma unroll
      for (int c = 0; c < 4; ++c) {
        #pragma unroll
        for (int ks = 0; ks < 2; ++ks) {
          const float* p = kp + (size_t)c * 16 * ROW + ks * 32 + qd * 8;
          f32x4 x = *(const f32x4*)(p);
          f32x4 y = *(const f32x4*)(p + 4);
          kf[c][ks].u[0] = pkbf(x[0], x[1]);
          kf[c][ks].u[1] = pkbf(x[2], x[3]);
          kf[c][ks].u[2] = pkbf(y[0], y[1]);
          kf[c][ks].u[3] = pkbf(y[2], y[3]);
        }
      }
    }

    __syncthreads();  // VT[t&1] staged; dbuf -> single barrier per tile

    // S^T = K·Q^T ; P = exp2(S^T) -> LDS (b64 packed writes)
    #pragma unroll
    for (int mt = 0; mt < MT; ++mt) {
      float ls = 0.f;
      #pragma unroll
      for (int c = 0; c < 4; ++c) {
        f32x4 s = {};
        s = __builtin_amdgcn_mfma_f32_16x16x32_bf16(kf[c][0].v, qf[mt][0].v, s, 0, 0, 0);
        s = __builtin_amdgcn_mfma_f32_16x16x32_bf16(kf[c][1].v, qf[mt][1].v, s, 0, 0, 0);
        float e0 = __builtin_amdgcn_exp2f(s[0]);
        float e1 = __builtin_amdgcn_exp2f(s[1]);
        float e2 = __builtin_amdgcn_exp2f(s[2]);
        float e3 = __builtin_amdgcn_exp2f(s[3]);
        ls += (e0 + e1) + (e2 + e3);
        int n = c * 16 + qd * 4;              // rows of S^T this lane holds
        int chunk = (n >> 3) ^ (lm & 7);
        u32x2 val; val.x = pkbf(e0, e1); val.y = pkbf(e2, e3);
        *(u32x2*)(PB[wave][mt] + lm * 64 + chunk * 8 + (n & 7)) = val;
      }
      lsum[mt] += ls;
    }

    __threadfence_block();  // order P writes vs typed re-reads (same wave)

    // O^T += V^T · P^T
    const unsigned short* vt = VT[t & 1];
    #pragma unroll
    for (int ks = 0; ks < 2; ++ks) {
      bf16x8 pfr[MT];
      #pragma unroll
      for (int mt = 0; mt < MT; ++mt) {
        int chunk = (ks * 4 + qd) ^ (lm & 7);
        pfr[mt] = *(const bf16x8*)(PB[wave][mt] + lm * 64 + chunk * 8);
      }
      #pragma unroll
      for (int dt = 0; dt < 4; ++dt) {
        int d = dt * 16 + lm;
        int chunk = (ks * 4 + qd) ^ (d & 7);
        bf16x8 vf = *(const bf16x8*)(vt + d * 64 + chunk * 8);
        #pragma unroll
        for (int mt = 0; mt < MT; ++mt)
          oacc[mt][dt] = __builtin_amdgcn_mfma_f32_16x16x32_bf16(vf, pfr[mt], oacc[mt][dt], 0, 0, 0);
      }
    }
  }

  // epilogue: l = sum over quads (deferred row-sum), write O (coalesced x4)
  #pragma unroll
  for (int mt = 0; mt < MT; ++mt) {
    float l = lsum[mt];
    l += __shfl_xor(l, 16, 64);
    l += __shfl_xor(l, 32, 64);
    float r = 1.0f / l;
    float* op = ob + (size_t)(qrow0 + mt * 16 + lm) * ROW + qd * 4;
    #pragma unroll
    for (int dt = 0; dt < 4; ++dt) {
      f32x4 o = oacc[mt][dt];
      o[0] *= r; o[1] *= r; o[2] *= r; o[3] *= r;
      *(f32x4*)(op + dt * 16) = o;
    }
  }
}

} // namespace

extern "C" void kernel_launch(void* const* d_in, const int* in_sizes, int n_in,
                              void* d_out, int out_size, void* d_ws, size_t ws_size,
                              hipStream_t stream) {
  const float* q = (const float*)d_in[0];
  const float* k = (const float*)d_in[1];
  const float* v = (const float*)d_in[2];
  float* o = (float*)d_out;
  (void)in_sizes; (void)n_in; (void)out_size; (void)d_ws; (void)ws_size;
  dim3 grid(2 * NH * (Sseq / BM));  // 1024 blocks: id = qblk*32 + (b*16+h)
  dim3 block(256);
  hipLaunchKernelGGL(fa_fwd, grid, block, 0, stream, q, k, v, o);
}

// Round 3
// 148.721 us; speedup vs baseline: 2.4352x; 2.4352x over previous
//
#include <hip/hip_runtime.h>
#include <hip/hip_bf16.h>

namespace {

constexpr int Sseq = 2048;
constexpr int NH   = 16;
constexpr int HD   = 64;
constexpr int ROW  = NH * HD;      // 1024 floats between consecutive s
constexpr int BM   = 128;          // q rows per block
constexpr int BN   = 64;           // kv rows per tile
constexpr int MT   = 2;            // 16-row m-tiles per wave
constexpr int NT   = Sseq / BN;    // 32 kv tiles
constexpr float QSCALE = 0.18033688011112042f; // (1/8) * log2(e)

typedef __bf16 bf16_t;
typedef __attribute__((ext_vector_type(8))) bf16_t bf16x8;
typedef __attribute__((ext_vector_type(4))) float f32x4;
typedef __attribute__((ext_vector_type(2))) unsigned int u32x2;
typedef __attribute__((ext_vector_type(4))) unsigned int u32x4;

union Frag { bf16x8 v; unsigned int u[4]; };

__device__ inline unsigned int pkbf(float a, float b) {
  union { __hip_bfloat162 h; unsigned int u; } x;
  x.h = __float22bfloat162_rn(make_float2(a, b));
  return x.u;
}

// mfma_f32_16x16x32_bf16: A[m=lane&15][k=quad*8+j], B[k=quad*8+j][n=lane&15],
// C/D: col=lane&15, row=quad*4+reg.
// S^T = K·Q^T (softmax state = lane scalar), O^T = V^T·P^T.
// LDS rows are 128B, 16B-chunk XOR swizzle (chunk ^= row&7).
//
// R3: R2 showed per-wave redundant K global load+cvt was the binding cost
// (time scaled with it; occupancy was irrelevant). K now staged in LDS bf16
// once per block (like V), K+V double-buffered, register prefetch of tile
// t+1 issued right after the single per-tile barrier.

__global__ __launch_bounds__(256)
void fa_fwd(const float* __restrict__ Q, const float* __restrict__ K,
            const float* __restrict__ V, float* __restrict__ O) {
  const int id   = blockIdx.x;
  const int bh   = id & 31;           // b*16 + h ; XCD = id % 8
  const int qblk = id >> 5;
  const int tid  = threadIdx.x;
  const int wave = tid >> 6;
  const int lane = tid & 63;
  const int qd   = lane >> 4;         // quad
  const int lm   = lane & 15;

  const size_t base = (size_t)(bh >> 4) * Sseq * ROW + (size_t)(bh & 15) * HD;
  const float* qb = Q + base;
  const float* kb = K + base;
  const float* vb = V + base;
  float*       ob = O + base;

  __shared__ __align__(16) unsigned short KT[2][HD * 64];     // K [kv][d] bf16 dbuf 16KB
  __shared__ __align__(16) unsigned short VT[2][HD * 64];     // V^T [d][kv] bf16 dbuf 16KB
  __shared__ __align__(16) unsigned short PB[4][MT][16 * 64]; // per-wave P 16KB

  const int qrow0 = qblk * BM + wave * (MT * 16);

  // Q B-fragments, pre-scaled by (1/sqrt(D))*log2(e) so p = exp2(s)
  Frag qf[MT][2];
  for (int mt = 0; mt < MT; ++mt) {
    const float* qp = qb + (size_t)(qrow0 + mt * 16 + lm) * ROW;
    for (int ks = 0; ks < 2; ++ks) {
      f32x4 a = *(const f32x4*)(qp + ks * 32 + qd * 8);
      f32x4 c = *(const f32x4*)(qp + ks * 32 + qd * 8 + 4);
      qf[mt][ks].u[0] = pkbf(a[0] * QSCALE, a[1] * QSCALE);
      qf[mt][ks].u[1] = pkbf(a[2] * QSCALE, a[3] * QSCALE);
      qf[mt][ks].u[2] = pkbf(c[0] * QSCALE, c[1] * QSCALE);
      qf[mt][ks].u[3] = pkbf(c[2] * QSCALE, c[3] * QSCALE);
    }
  }

  f32x4 oacc[MT][4] = {};
  float lsum[MT] = {};

  // staging assignments
  const int kr = tid >> 2;            // K: row kr, d = kd..kd+15
  const int kd = (tid & 3) * 16;
  const int n4 = (tid & 15) * 4;      // V: 4 kv-rows x 4 d-cols (transposed store)
  const int d4 = (tid >> 4) * 4;

  const float* kp = kb + (size_t)kr * ROW + kd;
  const float* vp = vb + (size_t)n4 * ROW + d4;

  // prologue: prefetch tile 0 into registers
  f32x4 kx0 = *(const f32x4*)(kp);
  f32x4 kx1 = *(const f32x4*)(kp + 4);
  f32x4 kx2 = *(const f32x4*)(kp + 8);
  f32x4 kx3 = *(const f32x4*)(kp + 12);
  f32x4 vx0 = *(const f32x4*)(vp);
  f32x4 vx1 = *(const f32x4*)(vp + ROW);
  f32x4 vx2 = *(const f32x4*)(vp + 2 * ROW);
  f32x4 vx3 = *(const f32x4*)(vp + 3 * ROW);

  for (int t = 0; t < NT; ++t) {
    unsigned short* kt = KT[t & 1];
    unsigned short* vt = VT[t & 1];

    { // stage K [kv][d] bf16, swizzled: two b128 writes
      int c0 = ((tid & 3) * 2) ^ (kr & 7);
      int c1 = ((tid & 3) * 2 + 1) ^ (kr & 7);
      u32x4 w0, w1;
      w0.x = pkbf(kx0[0], kx0[1]); w0.y = pkbf(kx0[2], kx0[3]);
      w0.z = pkbf(kx1[0], kx1[1]); w0.w = pkbf(kx1[2], kx1[3]);
      w1.x = pkbf(kx2[0], kx2[1]); w1.y = pkbf(kx2[2], kx2[3]);
      w1.z = pkbf(kx3[0], kx3[1]); w1.w = pkbf(kx3[2], kx3[3]);
      *(u32x4*)(kt + kr * 64 + c0 * 8) = w0;
      *(u32x4*)(kt + kr * 64 + c1 * 8) = w1;
    }
    { // stage V^T bf16, swizzled
      #pragma unroll
      for (int i = 0; i < 4; ++i) {
        int d = d4 + i;
        int chunk = (n4 >> 3) ^ (d & 7);
        u32x2 val; val.x = pkbf(vx0[i], vx1[i]); val.y = pkbf(vx2[i], vx3[i]);
        *(u32x2*)(vt + d * 64 + chunk * 8 + (n4 & 7)) = val;
      }
    }

    __syncthreads();  // buf (t&1) staged; dbuf -> single barrier per tile

    // issue global prefetch of tile t+1 (latency covered by compute below)
    if (t + 1 < NT) {
      kp += BN * ROW; vp += BN * ROW;
      kx0 = *(const f32x4*)(kp);
      kx1 = *(const f32x4*)(kp + 4);
      kx2 = *(const f32x4*)(kp + 8);
      kx3 = *(const f32x4*)(kp + 12);
      vx0 = *(const f32x4*)(vp);
      vx1 = *(const f32x4*)(vp + ROW);
      vx2 = *(const f32x4*)(vp + 2 * ROW);
      vx3 = *(const f32x4*)(vp + 3 * ROW);
    }

    // S^T = K·Q^T ; P = exp2(S^T) -> LDS (K frags from LDS, reused over mt)
    #pragma unroll
    for (int c = 0; c < 4; ++c) {
      Frag kf0, kf1;
      {
        int r = c * 16 + lm;
        int ch0 = (qd) ^ (lm & 7);
        int ch1 = (4 + qd) ^ (lm & 7);
        kf0.v = *(const bf16x8*)(kt + r * 64 + ch0 * 8);
        kf1.v = *(const bf16x8*)(kt + r * 64 + ch1 * 8);
      }
      #pragma unroll
      for (int mt = 0; mt < MT; ++mt) {
        f32x4 s = {};
        s = __builtin_amdgcn_mfma_f32_16x16x32_bf16(kf0.v, qf[mt][0].v, s, 0, 0, 0);
        s = __builtin_amdgcn_mfma_f32_16x16x32_bf16(kf1.v, qf[mt][1].v, s, 0, 0, 0);
        float e0 = __builtin_amdgcn_exp2f(s[0]);
        float e1 = __builtin_amdgcn_exp2f(s[1]);
        float e2 = __builtin_amdgcn_exp2f(s[2]);
        float e3 = __builtin_amdgcn_exp2f(s[3]);
        lsum[mt] += (e0 + e1) + (e2 + e3);
        int n = c * 16 + qd * 4;              // rows of S^T this lane holds
        int chunk = (n >> 3) ^ (lm & 7);
        u32x2 val; val.x = pkbf(e0, e1); val.y = pkbf(e2, e3);
        *(u32x2*)(PB[wave][mt] + lm * 64 + chunk * 8 + (n & 7)) = val;
      }
    }

    __threadfence_block();  // order P writes vs typed re-reads (same wave)

    // O^T += V^T · P^T
    #pragma unroll
    for (int ks = 0; ks < 2; ++ks) {
      bf16x8 pfr[MT];
      #pragma unroll
      for (int mt = 0; mt < MT; ++mt) {
        int chunk = (ks * 4 + qd) ^ (lm & 7);
        pfr[mt] = *(const bf16x8*)(PB[wave][mt] + lm * 64 + chunk * 8);
      }
      #pragma unroll
      for (int dt = 0; dt < 4; ++dt) {
        int d = dt * 16 + lm;
        int chunk = (ks * 4 + qd) ^ (d & 7);
        bf16x8 vf = *(const bf16x8*)(vt + d * 64 + chunk * 8);
        #pragma unroll
        for (int mt = 0; mt < MT; ++mt)
          oacc[mt][dt] = __builtin_amdgcn_mfma_f32_16x16x32_bf16(vf, pfr[mt], oacc[mt][dt], 0, 0, 0);
      }
    }
  }

  // epilogue: l = sum over quads, normalize, coalesced f32x4 stores
  #pragma unroll
  for (int mt = 0; mt < MT; ++mt) {
    float l = lsum[mt];
    l += __shfl_xor(l, 16, 64);
    l += __shfl_xor(l, 32, 64);
    float r = 1.0f / l;
    float* op = ob + (size_t)(qrow0 + mt * 16 + lm) * ROW + qd * 4;
    #pragma unroll
    for (int dt = 0; dt < 4; ++dt) {
      f32x4 o = oacc[mt][dt];
      o[0] *= r; o[1] *= r; o[2] *= r; o[3] *= r;
      *(f32x4*)(op + dt * 16) = o;
    }
  }
}

} // namespace

extern "C" void kernel_launch(void* const* d_in, const int* in_sizes, int n_in,
                              void* d_out, int out_size, void* d_ws, size_t ws_size,
                              hipStream_t stream) {
  const float* q = (const float*)d_in[0];
  const float* k = (const float*)d_in[1];
  const float* v = (const float*)d_in[2];
  float* o = (float*)d_out;
  (void)in_sizes; (void)n_in; (void)out_size; (void)d_ws; (void)ws_size;
  dim3 grid(2 * NH * (Sseq / BM));  // 512 blocks: id = qblk*32 + (b*16+h)
  dim3 block(256);
  hipLaunchKernelGGL(fa_fwd, grid, block, 0, stream, q, k, v, o);
}